// Round 1
// 358.730 us; speedup vs baseline: 1.1644x; 1.1644x over previous
//
#include <hip/hip_runtime.h>
#include <hip/hip_bf16.h>

typedef __attribute__((ext_vector_type(8))) short bf16x8;
typedef __attribute__((ext_vector_type(4))) short bf16x4;
typedef __attribute__((ext_vector_type(4))) float f32x4;
typedef __attribute__((address_space(3))) ushort lds_ushort;

#define MFMA32(a, b, c) __builtin_amdgcn_mfma_f32_16x16x32_bf16(a, b, c, 0, 0, 0)
#if __has_builtin(__builtin_amdgcn_mfma_f32_16x16x16bf16_1k)
#define HAVE_MFMA16K 1
#define MFMA16K(a, b, c) __builtin_amdgcn_mfma_f32_16x16x16bf16_1k(a, b, c, 0, 0, 0)
#else
#define HAVE_MFMA16K 0
#endif

// async global->LDS, 16B/lane; LDS dest = wave-uniform base + lane*16.
#define ASYNC16(g, l)                                                          \
    __builtin_amdgcn_global_load_lds(                                          \
        (const __attribute__((address_space(1))) unsigned int*)(g),            \
        (__attribute__((address_space(3))) unsigned int*)(l), 16, 0, 0)

// hw transpose read: per 16-lane group reads 128B window as 4x16 bf16
// row-major, lane l gets column (l&15). addr = window_base + (l&15)*8 bytes.
#define TR16(dst, addr, OFF)                                                   \
    asm volatile("ds_read_b64_tr_b16 %0, %1 offset:%2"                         \
                 : "=v"(dst) : "v"(addr), "i"(OFF))

__device__ __forceinline__ ushort f2bf(float f) {
    __hip_bfloat16 h = __float2bfloat16(f);  // RNE
    return *reinterpret_cast<ushort*>(&h);
}
// pack two positive f32 to bf16 pair, round-half-up (1 ulp-class error, cheap)
__device__ __forceinline__ uint pack_bf16_2(float a, float b) {
    uint ua = __float_as_uint(a) + 0x8000u;
    uint ub = __float_as_uint(b) + 0x8000u;
    return (ua >> 16) | (ub & 0xFFFF0000u);
}

// log2(e)/sqrt(64), folded into Q projection -> attn does exp2(score) raw.
#define QSCALE 0.18033688011112042f

// ---------------------------------------------------------------------------
// fp32 -> bf16 convert, multi-range.
// ---------------------------------------------------------------------------
struct CvtArgs { const float* s[7]; ushort* d[7]; int nb[7]; };

__global__ __launch_bounds__(256) void cvtk(CvtArgs a) {
    const int z = blockIdx.y;
    if ((int)blockIdx.x >= a.nb[z]) return;
    const float* s = a.s[z];
    ushort* d = a.d[z];
    const size_t i = (size_t)blockIdx.x * 2048 + threadIdx.x * 8;
    float4 f0 = *(const float4*)&s[i];
    float4 f1 = *(const float4*)&s[i + 4];
    *(ushort4*)&d[i]     = make_ushort4(f2bf(f0.x), f2bf(f0.y), f2bf(f0.z), f2bf(f0.w));
    *(ushort4*)&d[i + 4] = make_ushort4(f2bf(f1.x), f2bf(f1.y), f2bf(f1.z), f2bf(f1.w));
}

// ---------------------------------------------------------------------------
// bf16 NT GEMM (m97 structure, BK=32): out = (X@W^T + bias) * scale
//   mode 0: bf16 out [B=4,H=16,S=2048,64]  (Q scaled, K, V)
//   mode 2: fp32 out [8192,1024]           (final projection)
// ---------------------------------------------------------------------------
struct GemmArgs {
    const ushort* X[3]; const ushort* W[3]; const float* B[3];
    void* O[3]; int mode[3]; float scale[3];
};

__global__ __launch_bounds__(256) void gemm3(GemmArgs g) {
    __shared__ __attribute__((aligned(16))) ushort As[128][32];
    __shared__ __attribute__((aligned(16))) ushort Bs[128][32];

    const int z = blockIdx.z;
    const ushort* __restrict__ X = g.X[z];
    const ushort* __restrict__ W = g.W[z];
    const float*  __restrict__ bias = g.B[z];
    const int mode = g.mode[z];
    const float scale = g.scale[z];

    const int tid  = threadIdx.x;
    const int lane = tid & 63;
    const int wave = tid >> 6;
    const int quad = lane >> 4;
    const int l16  = lane & 15;
    const int wm   = (wave >> 1) * 64;
    const int wn   = (wave & 1) * 64;
    const int m0   = blockIdx.y * 128;
    const int n0   = blockIdx.x * 128;

    f32x4 acc[4][4];
#pragma unroll
    for (int i = 0; i < 4; i++)
#pragma unroll
        for (int j = 0; j < 4; j++) acc[i][j] = (f32x4)0.0f;

    for (int k0 = 0; k0 < 1024; k0 += 32) {
        __syncthreads();
        // 512 chunks of 16B per tile; chunk c: row c>>2, colq c&3.
#pragma unroll
        for (int j = 0; j < 2; j++) {
            const int c   = j * 256 + tid;
            const int r   = c >> 2;
            const int col = (c & 3) * 8;
            ASYNC16(&X[(size_t)(m0 + r) * 1024 + k0 + col],
                    &As[0][0] + (size_t)(j * 256 + wave * 64) * 8);
            ASYNC16(&W[(size_t)(n0 + r) * 1024 + k0 + col],
                    &Bs[0][0] + (size_t)(j * 256 + wave * 64) * 8);
        }
        __syncthreads();

        bf16x8 af[4], bfr[4];
#pragma unroll
        for (int i = 0; i < 4; i++)
            af[i] = *(const bf16x8*)&As[wm + i * 16 + l16][quad * 8];
#pragma unroll
        for (int j = 0; j < 4; j++)
            bfr[j] = *(const bf16x8*)&Bs[wn + j * 16 + l16][quad * 8];
#pragma unroll
        for (int i = 0; i < 4; i++)
#pragma unroll
            for (int j = 0; j < 4; j++)
                acc[i][j] = MFMA32(af[i], bfr[j], acc[i][j]);
    }

    // C/D: col = lane&15 (n), row = quad*4 + reg (m).
#pragma unroll
    for (int i = 0; i < 4; i++) {
#pragma unroll
        for (int j = 0; j < 4; j++) {
            const int n  = n0 + wn + j * 16 + l16;
            const float bb = bias[n];
#pragma unroll
            for (int r = 0; r < 4; r++) {
                const int m = m0 + wm + i * 16 + quad * 4 + r;
                const float val = (acc[i][j][r] + bb) * scale;
                if (mode == 2) {
                    ((float*)g.O[z])[(size_t)m * 1024 + n] = val;
                } else {
                    const int bat = m >> 11, s = m & 2047, h = n >> 6, d = n & 63;
                    ((ushort*)g.O[z])[((size_t)((bat * 16 + h) * 2048 + s)) * 64 + d]
                        = f2bf(val);
                }
            }
        }
    }
}

// ---------------------------------------------------------------------------
// Attention, P-in-registers. Block = (b,h) x 128 Q-rows; wave owns 32 rows.
// S^T = MFMA32(A=K, B=Q): lane holds (key=quad*4+r, query=l16) -> exp2 ->
// packed bf16 regs ARE the A-frag of a K=16 MFMA. V is staged via
// global_load_lds into a 4x16-subtiled layout V'[key>>2][d>>4][key&3][d&15]
// (source-address swizzle, LDS dest linear), and PV B-frags come from
// ds_read_b64_tr_b16 hardware transpose reads -> no software transpose,
// no bank-conflicted scalar ds_writes. K and V double-buffered, one barrier
// per tile (2-phase pipeline): next tile's async loads fly under compute.
// Row sums per-lane (query=l16), quad-reduced by shfl at the end.
// XCD swizzle: all 16 q-tiles of one bh on one XCD (id&7).
// ---------------------------------------------------------------------------
__global__ __launch_bounds__(256, 4) void attn(
    const ushort* __restrict__ Qp, const ushort* __restrict__ Kp,
    const ushort* __restrict__ Vp, ushort* __restrict__ ctx)
{
    __shared__ __attribute__((aligned(16))) ushort Ks[2][2 * 64 * 32];  // 2x8KB
    __shared__ __attribute__((aligned(16))) ushort Vs[2][64 * 64];      // 2x8KB

    const int tid  = threadIdx.x;
    const int lane = tid & 63;
    const int wave = tid >> 6;
    const int quad = lane >> 4;
    const int l16  = lane & 15;

    const int id = blockIdx.x;
    const int bh = (id & 7) * 8 + ((id >> 3) & 7);  // XCD-contiguous bh
    const int q0 = (id >> 6) * 128;
    const int b  = bh >> 4, h = bh & 15;

    const ushort* Qg = Qp + ((size_t)bh * 2048 + q0) * 64;
    const ushort* Kg = Kp + (size_t)bh * 2048 * 64;
    const ushort* Vg = Vp + (size_t)bh * 2048 * 64;

    // Loop-invariant Q fragments (B-operand: n=l16=query, k=quad*8+e).
    bf16x8 aq[2][2];
#pragma unroll
    for (int st = 0; st < 2; st++)
#pragma unroll
        for (int kk = 0; kk < 2; kk++)
            aq[st][kk] = *(const bf16x8*)&Qg[(size_t)(wave * 32 + st * 16 + l16) * 64
                                            + kk * 32 + quad * 8];

    f32x4 o[2][4];
#pragma unroll
    for (int st = 0; st < 2; st++)
#pragma unroll
        for (int jd = 0; jd < 4; jd++) o[st][jd] = (f32x4)0.0f;
    float lsum[2] = {0.f, 0.f};

    // K tile: natural [half][row][32] layout. V tile: 4x16-subtiled V' via
    // source-swizzled async chunks: chunk c -> keyg=c>>5, dg=(c>>3)&3,
    // kl=(c>>1)&3, half=c&1; global src stays 128B-coalesced per 8 lanes.
    auto stage = [&](int buf, int n0) {
#pragma unroll
        for (int j = 0; j < 2; j++) {
            const int c    = j * 256 + tid;
            const int colq = c & 3;
            const int row  = (c >> 2) & 63;
            const int half = c >> 8;
            ASYNC16(&Kg[(size_t)(n0 + row) * 64 + half * 32 + colq * 8],
                    &Ks[buf][0] + (size_t)(j * 256 + wave * 64) * 8);
        }
#pragma unroll
        for (int j = 0; j < 2; j++) {
            const int c   = j * 256 + tid;
            const int key = ((c >> 5) << 2) | ((c >> 1) & 3);
            const int d   = (((c >> 3) & 3) << 4) | ((c & 1) << 3);
            ASYNC16(&Vg[(size_t)(n0 + key) * 64 + d],
                    &Vs[buf][0] + (size_t)(j * 256 + wave * 64) * 8);
        }
    };

    stage(0, 0);
    int cur = 0;

    for (int n0 = 0; n0 < 2048; n0 += 64) {
        __syncthreads();  // drains vmcnt: buf 'cur' is ready; prev reads done
        if (n0 + 64 < 2048) stage(cur ^ 1, n0 + 64);  // flies under compute

        // ---- S^T: 8 tiles (kb keys x st strips), exp2 + pack in-register ----
        uint pk[4][2][2];
#pragma unroll
        for (int kb = 0; kb < 4; kb++) {
            bf16x8 kf0 = *(const bf16x8*)&Ks[cur][(size_t)(kb * 16 + l16) * 32 + quad * 8];
            bf16x8 kf1 = *(const bf16x8*)&Ks[cur][(size_t)(64 + kb * 16 + l16) * 32 + quad * 8];
#pragma unroll
            for (int st = 0; st < 2; st++) {
                f32x4 s = (f32x4)0.0f;
                s = MFMA32(kf0, aq[st][0], s);
                s = MFMA32(kf1, aq[st][1], s);
                float e0 = __builtin_amdgcn_exp2f(s[0]);
                float e1 = __builtin_amdgcn_exp2f(s[1]);
                float e2 = __builtin_amdgcn_exp2f(s[2]);
                float e3 = __builtin_amdgcn_exp2f(s[3]);
                lsum[st] += (e0 + e1) + (e2 + e3);
                pk[kb][st][0] = pack_bf16_2(e0, e1);
                pk[kb][st][1] = pack_bf16_2(e2, e3);
            }
        }

#if HAVE_MFMA16K
        // ---- PV: B-frags via hw transpose reads from subtiled V' ----
        // lane addr: window(keyg=kb*4+quad, dg=jd) + l16*8B; imm walks (kb,jd).
        const lds_ushort* vp = (const lds_ushort*)&Vs[cur][0] + quad * 256 + l16 * 4;
        bf16x4 vf[4][4];  // [jd][kb]
#define TRISSUE(JD)                                                            \
        TR16(vf[JD][0], vp, (JD) * 128 + 0);                                   \
        TR16(vf[JD][1], vp, (JD) * 128 + 2048);                                \
        TR16(vf[JD][2], vp, (JD) * 128 + 4096);                                \
        TR16(vf[JD][3], vp, (JD) * 128 + 6144);
        TRISSUE(0) TRISSUE(1) TRISSUE(2) TRISSUE(3)

        // counted lgkmcnt: jd group ready when <=12-4*jd outstanding (FIFO,
        // trs are oldest). sched_barrier(0) after each wait (rule #18).
#define PVWAIT(N)                                                              \
        asm volatile("s_waitcnt lgkmcnt(" #N ")" ::: "memory");                \
        __builtin_amdgcn_sched_barrier(0);
#define PVJD(JD)                                                               \
        _Pragma("unroll")                                                      \
        for (int kb = 0; kb < 4; kb++) {                                       \
            _Pragma("unroll")                                                  \
            for (int st = 0; st < 2; st++) {                                   \
                union { uint u[2]; bf16x4 v; } pf;                             \
                pf.u[0] = pk[kb][st][0];                                       \
                pf.u[1] = pk[kb][st][1];                                       \
                o[st][JD] = MFMA16K(pf.v, vf[JD][kb], o[st][JD]);              \
            }                                                                  \
        }
        __builtin_amdgcn_s_setprio(1);
        PVWAIT(12) PVJD(0)
        PVWAIT(8)  PVJD(1)
        PVWAIT(4)  PVJD(2)
        PVWAIT(0)  PVJD(3)
        __builtin_amdgcn_s_setprio(0);
#else
        // Fallback: assemble K=32 A-frags via ds_bpermute, gather V from the
        // subtiled V' with scalar reads, PV with MFMA32. (Correctness path.)
        const int addr0 = 4 * ((2 * (quad & 1)) * 16 + l16);
        const int addr1 = addr0 + 64;
#pragma unroll
        for (int kt = 0; kt < 2; kt++) {
            bf16x8 apf[2];
#pragma unroll
            for (int st = 0; st < 2; st++) {
                union { uint u[4]; bf16x8 v; } t;
#pragma unroll
                for (int j = 0; j < 4; j++) {
                    uint src = (quad & 2) ? pk[kt * 2 + 1][st][j & 1]
                                          : pk[kt * 2][st][j & 1];
                    t.u[j] = (uint)__builtin_amdgcn_ds_bpermute(
                        (j >> 1) ? addr1 : addr0, (int)src);
                }
                apf[st] = t.v;
            }
#pragma unroll
            for (int jd = 0; jd < 4; jd++) {
                union { ushort s[8]; bf16x8 v; } vv;
#pragma unroll
                for (int e = 0; e < 8; e++) {
                    const int key = kt * 32 + quad * 8 + e;
                    const int d   = jd * 16 + l16;
                    vv.s[e] = Vs[cur][(key >> 2) * 256 + (d >> 4) * 64
                                      + (key & 3) * 16 + (d & 15)];
                }
#pragma unroll
                for (int st = 0; st < 2; st++)
                    o[st][jd] = MFMA32(apf[st], vv.v, o[st][jd]);
            }
        }
#endif
        cur ^= 1;
    }

    // lsum holds per-(l16,quad) partials for query=l16: reduce over quads.
#pragma unroll
    for (int st = 0; st < 2; st++) {
        float ls = lsum[st];
        ls += __shfl_xor(ls, 16, 64);
        ls += __shfl_xor(ls, 32, 64);
        // O rows are query = quad*4+r: fetch that query's sum via shfl.
        float inv[4];
#pragma unroll
        for (int r = 0; r < 4; r++)
            inv[r] = 1.0f / __shfl(ls, quad * 4 + r, 64);
#pragma unroll
        for (int jd = 0; jd < 4; jd++) {
#pragma unroll
            for (int r = 0; r < 4; r++) {
                const int s = q0 + wave * 32 + st * 16 + quad * 4 + r;
                ctx[((size_t)(b * 2048 + s)) * 1024 + h * 64 + jd * 16 + l16] =
                    f2bf(o[st][jd][r] * inv[r]);
            }
        }
    }
}

extern "C" void kernel_launch(void* const* d_in, const int* in_sizes, int n_in,
                              void* d_out, int out_size, void* d_ws, size_t ws_size,
                              hipStream_t stream) {
    const float* q    = (const float*)d_in[0];
    const float* k    = (const float*)d_in[1];
    const float* v    = (const float*)d_in[2];
    const float* wq_w = (const float*)d_in[3];
    const float* wq_b = (const float*)d_in[4];
    const float* wk_w = (const float*)d_in[5];
    const float* wk_b = (const float*)d_in[6];
    const float* wv_w = (const float*)d_in[7];
    const float* wv_b = (const float*)d_in[8];
    const float* wo_w = (const float*)d_in[9];
    const float* wo_b = (const float*)d_in[10];
    float* out = (float*)d_out;

    const size_t NE = (size_t)4 * 2048 * 1024;
    const size_t NW = (size_t)1024 * 1024;
    const size_t need_fused = (6 * NE + 4 * NW) * 2;

    dim3 blk(256);

    if (ws_size >= need_fused) {
        ushort* Xq = (ushort*)d_ws;
        ushort* Xk = Xq + NE;
        ushort* Xv = Xk + NE;
        ushort* Wq = Xv + NE;
        ushort* Wk = Wq + NW;
        ushort* Wv = Wk + NW;
        ushort* Wo = Wv + NW;
        ushort* Qp = Wo + NW;
        ushort* Kp = Qp + NE;
        ushort* Vp = Kp + NE;
        ushort* ctx = Xq;

        CvtArgs ca;
        ca.s[0]=q;    ca.d[0]=Xq; ca.nb[0]=4096;
        ca.s[1]=k;    ca.d[1]=Xk; ca.nb[1]=4096;
        ca.s[2]=v;    ca.d[2]=Xv; ca.nb[2]=4096;
        ca.s[3]=wq_w; ca.d[3]=Wq; ca.nb[3]=512;
        ca.s[4]=wk_w; ca.d[4]=Wk; ca.nb[4]=512;
        ca.s[5]=wv_w; ca.d[5]=Wv; ca.nb[5]=512;
        ca.s[6]=wo_w; ca.d[6]=Wo; ca.nb[6]=512;
        cvtk<<<dim3(4096, 7), blk, 0, stream>>>(ca);

        GemmArgs ga;
        ga.X[0]=Xq; ga.W[0]=Wq; ga.B[0]=wq_b; ga.O[0]=Qp; ga.mode[0]=0; ga.scale[0]=QSCALE;
        ga.X[1]=Xk; ga.W[1]=Wk; ga.B[1]=wk_b; ga.O[1]=Kp; ga.mode[1]=0; ga.scale[1]=1.0f;
        ga.X[2]=Xv; ga.W[2]=Wv; ga.B[2]=wv_b; ga.O[2]=Vp; ga.mode[2]=0; ga.scale[2]=1.0f;
        gemm3<<<dim3(8, 64, 3), blk, 0, stream>>>(ga);

        attn<<<dim3(1024), blk, 0, stream>>>(Qp, Kp, Vp, ctx);

        GemmArgs go;
        go.X[0]=ctx; go.W[0]=Wo; go.B[0]=wo_b; go.O[0]=out; go.mode[0]=2; go.scale[0]=1.0f;
        go.X[1]=go.X[0]; go.W[1]=go.W[0]; go.B[1]=go.B[0]; go.O[1]=go.O[0]; go.mode[1]=2; go.scale[1]=1.0f;
        go.X[2]=go.X[0]; go.W[2]=go.W[0]; go.B[2]=go.B[0]; go.O[2]=go.O[0]; go.mode[2]=2; go.scale[2]=1.0f;
        gemm3<<<dim3(8, 64, 1), blk, 0, stream>>>(go);
    } else {
        // Serial fallback (68 MB): Xb reused per projection, then as ctx.
        ushort* Xb  = (ushort*)d_ws;
        ushort* Wb  = Xb + NE;
        ushort* Wob = Wb + NW;
        ushort* Qp  = Wob + NW;
        ushort* Kp  = Qp + NE;
        ushort* Vp  = Kp + NE;
        ushort* ctx = Xb;

        CvtArgs c0;
        c0.s[0]=q;    c0.d[0]=Xb;  c0.nb[0]=4096;
        c0.s[1]=wq_w; c0.d[1]=Wb;  c0.nb[1]=512;
        c0.s[2]=wo_w; c0.d[2]=Wob; c0.nb[2]=512;
        for (int i = 3; i < 7; i++) { c0.s[i]=q; c0.d[i]=Xb; c0.nb[i]=0; }
        cvtk<<<dim3(4096, 3), blk, 0, stream>>>(c0);
        GemmArgs ga;
        for (int i = 0; i < 3; i++) { ga.X[i]=Xb; ga.W[i]=Wb; ga.B[i]=wq_b; ga.O[i]=Qp; ga.mode[i]=0; ga.scale[i]=QSCALE; }
        gemm3<<<dim3(8, 64, 1), blk, 0, stream>>>(ga);

        CvtArgs c1;
        c1.s[0]=k;    c1.d[0]=Xb; c1.nb[0]=4096;
        c1.s[1]=wk_w; c1.d[1]=Wb; c1.nb[1]=512;
        for (int i = 2; i < 7; i++) { c1.s[i]=k; c1.d[i]=Xb; c1.nb[i]=0; }
        cvtk<<<dim3(4096, 2), blk, 0, stream>>>(c1);
        GemmArgs gb;
        for (int i = 0; i < 3; i++) { gb.X[i]=Xb; gb.W[i]=Wb; gb.B[i]=wk_b; gb.O[i]=Kp; gb.mode[i]=0; gb.scale[i]=1.0f; }
        gemm3<<<dim3(8, 64, 1), blk, 0, stream>>>(gb);

        CvtArgs c2;
        c2.s[0]=v;    c2.d[0]=Xb; c2.nb[0]=4096;
        c2.s[1]=wv_w; c2.d[1]=Wb; c2.nb[1]=512;
        for (int i = 2; i < 7; i++) { c2.s[i]=v; c2.d[i]=Xb; c2.nb[i]=0; }
        cvtk<<<dim3(4096, 2), blk, 0, stream>>>(c2);
        GemmArgs gc;
        for (int i = 0; i < 3; i++) { gc.X[i]=Xb; gc.W[i]=Wb; gc.B[i]=wv_b; gc.O[i]=Vp; gc.mode[i]=0; gc.scale[i]=1.0f; }
        gemm3<<<dim3(8, 64, 1), blk, 0, stream>>>(gc);

        attn<<<dim3(1024), blk, 0, stream>>>(Qp, Kp, Vp, ctx);

        GemmArgs go;
        for (int i = 0; i < 3; i++) { go.X[i]=ctx; go.W[i]=Wob; go.B[i]=wo_b; go.O[i]=out; go.mode[i]=2; go.scale[i]=1.0f; }
        gemm3<<<dim3(8, 64, 1), blk, 0, stream>>>(go);
    }
}

// Round 2
// 350.849 us; speedup vs baseline: 1.1906x; 1.0225x over previous
//
#include <hip/hip_runtime.h>
#include <hip/hip_bf16.h>

typedef __attribute__((ext_vector_type(8))) short bf16x8;
typedef __attribute__((ext_vector_type(4))) short bf16x4;
typedef __attribute__((ext_vector_type(4))) float f32x4;
typedef __attribute__((address_space(3))) ushort lds_ushort;

#define MFMA32(a, b, c) __builtin_amdgcn_mfma_f32_16x16x32_bf16(a, b, c, 0, 0, 0)
#if __has_builtin(__builtin_amdgcn_mfma_f32_16x16x16bf16_1k)
#define HAVE_MFMA16K 1
#define MFMA16K(a, b, c) __builtin_amdgcn_mfma_f32_16x16x16bf16_1k(a, b, c, 0, 0, 0)
#else
#define HAVE_MFMA16K 0
#endif

// async global->LDS, 16B/lane; LDS dest = wave-uniform base + lane*16.
#define ASYNC16(g, l)                                                          \
    __builtin_amdgcn_global_load_lds(                                          \
        (const __attribute__((address_space(1))) unsigned int*)(g),            \
        (__attribute__((address_space(3))) unsigned int*)(l), 16, 0, 0)

// hw transpose read: per 16-lane group reads 128B window as 4x16 bf16
// row-major, lane l gets column (l&15). addr = window_base + (l&15)*8 bytes.
#define TR16(dst, addr, OFF)                                                   \
    asm volatile("ds_read_b64_tr_b16 %0, %1 offset:%2"                         \
                 : "=v"(dst) : "v"(addr), "i"(OFF))

__device__ __forceinline__ ushort f2bf(float f) {
    __hip_bfloat16 h = __float2bfloat16(f);  // RNE
    return *reinterpret_cast<ushort*>(&h);
}
// pack two positive f32 to bf16 pair, round-half-up (1 ulp-class error, cheap)
__device__ __forceinline__ uint pack_bf16_2(float a, float b) {
    uint ua = __float_as_uint(a) + 0x8000u;
    uint ub = __float_as_uint(b) + 0x8000u;
    return (ua >> 16) | (ub & 0xFFFF0000u);
}

// log2(e)/sqrt(64), folded into Q projection -> attn does exp2(score) raw.
#define QSCALE 0.18033688011112042f

// ---------------------------------------------------------------------------
// fp32 -> bf16 convert, multi-range.
// ---------------------------------------------------------------------------
struct CvtArgs { const float* s[7]; ushort* d[7]; int nb[7]; };

__global__ __launch_bounds__(256) void cvtk(CvtArgs a) {
    const int z = blockIdx.y;
    if ((int)blockIdx.x >= a.nb[z]) return;
    const float* s = a.s[z];
    ushort* d = a.d[z];
    const size_t i = (size_t)blockIdx.x * 2048 + threadIdx.x * 8;
    float4 f0 = *(const float4*)&s[i];
    float4 f1 = *(const float4*)&s[i + 4];
    *(ushort4*)&d[i]     = make_ushort4(f2bf(f0.x), f2bf(f0.y), f2bf(f0.z), f2bf(f0.w));
    *(ushort4*)&d[i + 4] = make_ushort4(f2bf(f1.x), f2bf(f1.y), f2bf(f1.z), f2bf(f1.w));
}

// ---------------------------------------------------------------------------
// bf16 NT GEMM: out = (X@W^T + bias) * scale
//   mode 0: bf16 out [B=4,H=16,S=2048,64]  (Q scaled, K, V)
//   mode 2: fp32 out [8192,1024]           (final projection)
// R1: double-buffered 2-phase K-loop (one barrier per step; next tile's
// global_load_lds fly under current tile's MFMA) + bijective XCD swizzle:
// hw linear id within z is x+8y (512 wgs, 512%8==0), xcd = flat%8. Remap so
// XCD k owns all 8 n-tiles of m-tiles [8k,8k+8): per-XCD L2 footprint is
// 2MB X-panel + 2MB W = 4MB (=L2); X read once globally, W once per XCD.
// ---------------------------------------------------------------------------
struct GemmArgs {
    const ushort* X[3]; const ushort* W[3]; const float* B[3];
    void* O[3]; int mode[3]; float scale[3];
};

__global__ __launch_bounds__(256) void gemm3(GemmArgs g) {
    __shared__ __attribute__((aligned(16))) ushort As[2][128][32];
    __shared__ __attribute__((aligned(16))) ushort Bs[2][128][32];

    const int z = blockIdx.z;
    const ushort* __restrict__ X = g.X[z];
    const ushort* __restrict__ W = g.W[z];
    const float*  __restrict__ bias = g.B[z];
    const int mode = g.mode[z];
    const float scale = g.scale[z];

    const int tid  = threadIdx.x;
    const int lane = tid & 63;
    const int wave = tid >> 6;
    const int quad = lane >> 4;
    const int l16  = lane & 15;
    const int wm   = (wave >> 1) * 64;
    const int wn   = (wave & 1) * 64;

    const int flat = blockIdx.x + 8 * blockIdx.y;
    const int t    = (flat & 7) * 64 + (flat >> 3);
    const int m0   = (t >> 3) * 128;
    const int n0   = (t & 7) * 128;

    f32x4 acc[4][4];
#pragma unroll
    for (int i = 0; i < 4; i++)
#pragma unroll
        for (int j = 0; j < 4; j++) acc[i][j] = (f32x4)0.0f;

    // 512 chunks of 16B per tile per matrix; chunk c: row c>>2, colq c&3.
    auto stage = [&](int buf, int k0) {
#pragma unroll
        for (int j = 0; j < 2; j++) {
            const int c   = j * 256 + tid;
            const int r   = c >> 2;
            const int col = (c & 3) * 8;
            ASYNC16(&X[(size_t)(m0 + r) * 1024 + k0 + col],
                    &As[buf][0][0] + (size_t)(j * 256 + wave * 64) * 8);
            ASYNC16(&W[(size_t)(n0 + r) * 1024 + k0 + col],
                    &Bs[buf][0][0] + (size_t)(j * 256 + wave * 64) * 8);
        }
    };

    stage(0, 0);
    int cur = 0;

    for (int k0 = 0; k0 < 1024; k0 += 32) {
        __syncthreads();  // implicit vmcnt(0): buf 'cur' ready, prev reads done
        if (k0 + 32 < 1024) stage(cur ^ 1, k0 + 32);  // flies under compute

        bf16x8 af[4], bfr[4];
#pragma unroll
        for (int i = 0; i < 4; i++)
            af[i] = *(const bf16x8*)&As[cur][wm + i * 16 + l16][quad * 8];
#pragma unroll
        for (int j = 0; j < 4; j++)
            bfr[j] = *(const bf16x8*)&Bs[cur][wn + j * 16 + l16][quad * 8];
#pragma unroll
        for (int i = 0; i < 4; i++)
#pragma unroll
            for (int j = 0; j < 4; j++)
                acc[i][j] = MFMA32(af[i], bfr[j], acc[i][j]);
        cur ^= 1;
    }

    // C/D: col = lane&15 (n), row = quad*4 + reg (m).
#pragma unroll
    for (int i = 0; i < 4; i++) {
#pragma unroll
        for (int j = 0; j < 4; j++) {
            const int n  = n0 + wn + j * 16 + l16;
            const float bb = bias[n];
#pragma unroll
            for (int r = 0; r < 4; r++) {
                const int m = m0 + wm + i * 16 + quad * 4 + r;
                const float val = (acc[i][j][r] + bb) * scale;
                if (mode == 2) {
                    ((float*)g.O[z])[(size_t)m * 1024 + n] = val;
                } else {
                    const int bat = m >> 11, s = m & 2047, h = n >> 6, d = n & 63;
                    ((ushort*)g.O[z])[((size_t)((bat * 16 + h) * 2048 + s)) * 64 + d]
                        = f2bf(val);
                }
            }
        }
    }
}

// ---------------------------------------------------------------------------
// Attention, P-in-registers. Block = (b,h) x 128 Q-rows; wave owns 32 rows.
// S^T = MFMA32(A=K, B=Q): lane holds (key=quad*4+r, query=l16) -> exp2 ->
// packed bf16 regs ARE the A-frag of a K=16 MFMA. V is staged via
// global_load_lds into a 4x16-subtiled layout V'[key>>2][d>>4][key&3][d&15]
// (source-address swizzle, LDS dest linear), and PV B-frags come from
// ds_read_b64_tr_b16 hardware transpose reads -> no software transpose,
// no bank-conflicted scalar ds_writes. K and V double-buffered, one barrier
// per tile (2-phase pipeline): next tile's async loads fly under compute.
// Row sums per-lane (query=l16), quad-reduced by shfl at the end.
// XCD swizzle: all 16 q-tiles of one bh on one XCD (id&7).
// ---------------------------------------------------------------------------
__global__ __launch_bounds__(256, 4) void attn(
    const ushort* __restrict__ Qp, const ushort* __restrict__ Kp,
    const ushort* __restrict__ Vp, ushort* __restrict__ ctx)
{
    __shared__ __attribute__((aligned(16))) ushort Ks[2][2 * 64 * 32];  // 2x8KB
    __shared__ __attribute__((aligned(16))) ushort Vs[2][64 * 64];      // 2x8KB

    const int tid  = threadIdx.x;
    const int lane = tid & 63;
    const int wave = tid >> 6;
    const int quad = lane >> 4;
    const int l16  = lane & 15;

    const int id = blockIdx.x;
    const int bh = (id & 7) * 8 + ((id >> 3) & 7);  // XCD-contiguous bh
    const int q0 = (id >> 6) * 128;
    const int b  = bh >> 4, h = bh & 15;

    const ushort* Qg = Qp + ((size_t)bh * 2048 + q0) * 64;
    const ushort* Kg = Kp + (size_t)bh * 2048 * 64;
    const ushort* Vg = Vp + (size_t)bh * 2048 * 64;

    // Loop-invariant Q fragments (B-operand: n=l16=query, k=quad*8+e).
    bf16x8 aq[2][2];
#pragma unroll
    for (int st = 0; st < 2; st++)
#pragma unroll
        for (int kk = 0; kk < 2; kk++)
            aq[st][kk] = *(const bf16x8*)&Qg[(size_t)(wave * 32 + st * 16 + l16) * 64
                                            + kk * 32 + quad * 8];

    f32x4 o[2][4];
#pragma unroll
    for (int st = 0; st < 2; st++)
#pragma unroll
        for (int jd = 0; jd < 4; jd++) o[st][jd] = (f32x4)0.0f;
    float lsum[2] = {0.f, 0.f};

    // K tile: natural [half][row][32] layout. V tile: 4x16-subtiled V' via
    // source-swizzled async chunks: chunk c -> keyg=c>>5, dg=(c>>3)&3,
    // kl=(c>>1)&3, half=c&1; global src stays 128B-coalesced per 8 lanes.
    auto stage = [&](int buf, int n0) {
#pragma unroll
        for (int j = 0; j < 2; j++) {
            const int c    = j * 256 + tid;
            const int colq = c & 3;
            const int row  = (c >> 2) & 63;
            const int half = c >> 8;
            ASYNC16(&Kg[(size_t)(n0 + row) * 64 + half * 32 + colq * 8],
                    &Ks[buf][0] + (size_t)(j * 256 + wave * 64) * 8);
        }
#pragma unroll
        for (int j = 0; j < 2; j++) {
            const int c   = j * 256 + tid;
            const int key = ((c >> 5) << 2) | ((c >> 1) & 3);
            const int d   = (((c >> 3) & 3) << 4) | ((c & 1) << 3);
            ASYNC16(&Vg[(size_t)(n0 + key) * 64 + d],
                    &Vs[buf][0] + (size_t)(j * 256 + wave * 64) * 8);
        }
    };

    stage(0, 0);
    int cur = 0;

    for (int n0 = 0; n0 < 2048; n0 += 64) {
        __syncthreads();  // drains vmcnt: buf 'cur' is ready; prev reads done
        if (n0 + 64 < 2048) stage(cur ^ 1, n0 + 64);  // flies under compute

        // ---- S^T: 8 tiles (kb keys x st strips), exp2 + pack in-register ----
        uint pk[4][2][2];
#pragma unroll
        for (int kb = 0; kb < 4; kb++) {
            bf16x8 kf0 = *(const bf16x8*)&Ks[cur][(size_t)(kb * 16 + l16) * 32 + quad * 8];
            bf16x8 kf1 = *(const bf16x8*)&Ks[cur][(size_t)(64 + kb * 16 + l16) * 32 + quad * 8];
#pragma unroll
            for (int st = 0; st < 2; st++) {
                f32x4 s = (f32x4)0.0f;
                s = MFMA32(kf0, aq[st][0], s);
                s = MFMA32(kf1, aq[st][1], s);
                float e0 = __builtin_amdgcn_exp2f(s[0]);
                float e1 = __builtin_amdgcn_exp2f(s[1]);
                float e2 = __builtin_amdgcn_exp2f(s[2]);
                float e3 = __builtin_amdgcn_exp2f(s[3]);
                lsum[st] += (e0 + e1) + (e2 + e3);
                pk[kb][st][0] = pack_bf16_2(e0, e1);
                pk[kb][st][1] = pack_bf16_2(e2, e3);
            }
        }

#if HAVE_MFMA16K
        // ---- PV: B-frags via hw transpose reads from subtiled V' ----
        // lane addr: window(keyg=kb*4+quad, dg=jd) + l16*8B; imm walks (kb,jd).
        const lds_ushort* vp = (const lds_ushort*)&Vs[cur][0] + quad * 256 + l16 * 4;
        bf16x4 vf[4][4];  // [jd][kb]
#define TRISSUE(JD)                                                            \
        TR16(vf[JD][0], vp, (JD) * 128 + 0);                                   \
        TR16(vf[JD][1], vp, (JD) * 128 + 2048);                                \
        TR16(vf[JD][2], vp, (JD) * 128 + 4096);                                \
        TR16(vf[JD][3], vp, (JD) * 128 + 6144);
        TRISSUE(0) TRISSUE(1) TRISSUE(2) TRISSUE(3)

        // counted lgkmcnt: jd group ready when <=12-4*jd outstanding (FIFO,
        // trs are oldest). sched_barrier(0) after each wait (rule #18).
#define PVWAIT(N)                                                              \
        asm volatile("s_waitcnt lgkmcnt(" #N ")" ::: "memory");                \
        __builtin_amdgcn_sched_barrier(0);
#define PVJD(JD)                                                               \
        _Pragma("unroll")                                                      \
        for (int kb = 0; kb < 4; kb++) {                                       \
            _Pragma("unroll")                                                  \
            for (int st = 0; st < 2; st++) {                                   \
                union { uint u[2]; bf16x4 v; } pf;                             \
                pf.u[0] = pk[kb][st][0];                                       \
                pf.u[1] = pk[kb][st][1];                                       \
                o[st][JD] = MFMA16K(pf.v, vf[JD][kb], o[st][JD]);              \
            }                                                                  \
        }
        __builtin_amdgcn_s_setprio(1);
        PVWAIT(12) PVJD(0)
        PVWAIT(8)  PVJD(1)
        PVWAIT(4)  PVJD(2)
        PVWAIT(0)  PVJD(3)
        __builtin_amdgcn_s_setprio(0);
#else
        // Fallback: assemble K=32 A-frags via ds_bpermute, gather V from the
        // subtiled V' with scalar reads, PV with MFMA32. (Correctness path.)
        const int addr0 = 4 * ((2 * (quad & 1)) * 16 + l16);
        const int addr1 = addr0 + 64;
#pragma unroll
        for (int kt = 0; kt < 2; kt++) {
            bf16x8 apf[2];
#pragma unroll
            for (int st = 0; st < 2; st++) {
                union { uint u[4]; bf16x8 v; } t;
#pragma unroll
                for (int j = 0; j < 4; j++) {
                    uint src = (quad & 2) ? pk[kt * 2 + 1][st][j & 1]
                                          : pk[kt * 2][st][j & 1];
                    t.u[j] = (uint)__builtin_amdgcn_ds_bpermute(
                        (j >> 1) ? addr1 : addr0, (int)src);
                }
                apf[st] = t.v;
            }
#pragma unroll
            for (int jd = 0; jd < 4; jd++) {
                union { ushort s[8]; bf16x8 v; } vv;
#pragma unroll
                for (int e = 0; e < 8; e++) {
                    const int key = kt * 32 + quad * 8 + e;
                    const int d   = jd * 16 + l16;
                    vv.s[e] = Vs[cur][(key >> 2) * 256 + (d >> 4) * 64
                                      + (key & 3) * 16 + (d & 15)];
                }
#pragma unroll
                for (int st = 0; st < 2; st++)
                    o[st][jd] = MFMA32(apf[st], vv.v, o[st][jd]);
            }
        }
#endif
        cur ^= 1;
    }

    // lsum holds per-(l16,quad) partials for query=l16: reduce over quads.
#pragma unroll
    for (int st = 0; st < 2; st++) {
        float ls = lsum[st];
        ls += __shfl_xor(ls, 16, 64);
        ls += __shfl_xor(ls, 32, 64);
        // O rows are query = quad*4+r: fetch that query's sum via shfl.
        float inv[4];
#pragma unroll
        for (int r = 0; r < 4; r++)
            inv[r] = 1.0f / __shfl(ls, quad * 4 + r, 64);
#pragma unroll
        for (int jd = 0; jd < 4; jd++) {
#pragma unroll
            for (int r = 0; r < 4; r++) {
                const int s = q0 + wave * 32 + st * 16 + quad * 4 + r;
                ctx[((size_t)(b * 2048 + s)) * 1024 + h * 64 + jd * 16 + l16] =
                    f2bf(o[st][jd][r] * inv[r]);
            }
        }
    }
}

extern "C" void kernel_launch(void* const* d_in, const int* in_sizes, int n_in,
                              void* d_out, int out_size, void* d_ws, size_t ws_size,
                              hipStream_t stream) {
    const float* q    = (const float*)d_in[0];
    const float* k    = (const float*)d_in[1];
    const float* v    = (const float*)d_in[2];
    const float* wq_w = (const float*)d_in[3];
    const float* wq_b = (const float*)d_in[4];
    const float* wk_w = (const float*)d_in[5];
    const float* wk_b = (const float*)d_in[6];
    const float* wv_w = (const float*)d_in[7];
    const float* wv_b = (const float*)d_in[8];
    const float* wo_w = (const float*)d_in[9];
    const float* wo_b = (const float*)d_in[10];
    float* out = (float*)d_out;

    const size_t NE = (size_t)4 * 2048 * 1024;
    const size_t NW = (size_t)1024 * 1024;
    const size_t need_fused = (6 * NE + 4 * NW) * 2;

    dim3 blk(256);

    if (ws_size >= need_fused) {
        ushort* Xq = (ushort*)d_ws;
        ushort* Xk = Xq + NE;
        ushort* Xv = Xk + NE;
        ushort* Wq = Xv + NE;
        ushort* Wk = Wq + NW;
        ushort* Wv = Wk + NW;
        ushort* Wo = Wv + NW;
        ushort* Qp = Wo + NW;
        ushort* Kp = Qp + NE;
        ushort* Vp = Kp + NE;
        ushort* ctx = Xq;

        CvtArgs ca;
        ca.s[0]=q;    ca.d[0]=Xq; ca.nb[0]=4096;
        ca.s[1]=k;    ca.d[1]=Xk; ca.nb[1]=4096;
        ca.s[2]=v;    ca.d[2]=Xv; ca.nb[2]=4096;
        ca.s[3]=wq_w; ca.d[3]=Wq; ca.nb[3]=512;
        ca.s[4]=wk_w; ca.d[4]=Wk; ca.nb[4]=512;
        ca.s[5]=wv_w; ca.d[5]=Wv; ca.nb[5]=512;
        ca.s[6]=wo_w; ca.d[6]=Wo; ca.nb[6]=512;
        cvtk<<<dim3(4096, 7), blk, 0, stream>>>(ca);

        GemmArgs ga;
        ga.X[0]=Xq; ga.W[0]=Wq; ga.B[0]=wq_b; ga.O[0]=Qp; ga.mode[0]=0; ga.scale[0]=QSCALE;
        ga.X[1]=Xk; ga.W[1]=Wk; ga.B[1]=wk_b; ga.O[1]=Kp; ga.mode[1]=0; ga.scale[1]=1.0f;
        ga.X[2]=Xv; ga.W[2]=Wv; ga.B[2]=wv_b; ga.O[2]=Vp; ga.mode[2]=0; ga.scale[2]=1.0f;
        gemm3<<<dim3(8, 64, 3), blk, 0, stream>>>(ga);

        attn<<<dim3(1024), blk, 0, stream>>>(Qp, Kp, Vp, ctx);

        GemmArgs go;
        go.X[0]=ctx; go.W[0]=Wo; go.B[0]=wo_b; go.O[0]=out; go.mode[0]=2; go.scale[0]=1.0f;
        go.X[1]=go.X[0]; go.W[1]=go.W[0]; go.B[1]=go.B[0]; go.O[1]=go.O[0]; go.mode[1]=2; go.scale[1]=1.0f;
        go.X[2]=go.X[0]; go.W[2]=go.W[0]; go.B[2]=go.B[0]; go.O[2]=go.O[0]; go.mode[2]=2; go.scale[2]=1.0f;
        gemm3<<<dim3(8, 64, 1), blk, 0, stream>>>(go);
    } else {
        // Serial fallback (68 MB): Xb reused per projection, then as ctx.
        ushort* Xb  = (ushort*)d_ws;
        ushort* Wb  = Xb + NE;
        ushort* Wob = Wb + NW;
        ushort* Qp  = Wob + NW;
        ushort* Kp  = Qp + NE;
        ushort* Vp  = Kp + NE;
        ushort* ctx = Xb;

        CvtArgs c0;
        c0.s[0]=q;    c0.d[0]=Xb;  c0.nb[0]=4096;
        c0.s[1]=wq_w; c0.d[1]=Wb;  c0.nb[1]=512;
        c0.s[2]=wo_w; c0.d[2]=Wob; c0.nb[2]=512;
        for (int i = 3; i < 7; i++) { c0.s[i]=q; c0.d[i]=Xb; c0.nb[i]=0; }
        cvtk<<<dim3(4096, 3), blk, 0, stream>>>(c0);
        GemmArgs ga;
        for (int i = 0; i < 3; i++) { ga.X[i]=Xb; ga.W[i]=Wb; ga.B[i]=wq_b; ga.O[i]=Qp; ga.mode[i]=0; ga.scale[i]=QSCALE; }
        gemm3<<<dim3(8, 64, 1), blk, 0, stream>>>(ga);

        CvtArgs c1;
        c1.s[0]=k;    c1.d[0]=Xb; c1.nb[0]=4096;
        c1.s[1]=wk_w; c1.d[1]=Wb; c1.nb[1]=512;
        for (int i = 2; i < 7; i++) { c1.s[i]=k; c1.d[i]=Xb; c1.nb[i]=0; }
        cvtk<<<dim3(4096, 2), blk, 0, stream>>>(c1);
        GemmArgs gb;
        for (int i = 0; i < 3; i++) { gb.X[i]=Xb; gb.W[i]=Wb; gb.B[i]=wk_b; gb.O[i]=Kp; gb.mode[i]=0; gb.scale[i]=1.0f; }
        gemm3<<<dim3(8, 64, 1), blk, 0, stream>>>(gb);

        CvtArgs c2;
        c2.s[0]=v;    c2.d[0]=Xb; c2.nb[0]=4096;
        c2.s[1]=wv_w; c2.d[1]=Wb; c2.nb[1]=512;
        for (int i = 2; i < 7; i++) { c2.s[i]=v; c2.d[i]=Xb; c2.nb[i]=0; }
        cvtk<<<dim3(4096, 2), blk, 0, stream>>>(c2);
        GemmArgs gc;
        for (int i = 0; i < 3; i++) { gc.X[i]=Xb; gc.W[i]=Wb; gc.B[i]=wv_b; gc.O[i]=Vp; gc.mode[i]=0; gc.scale[i]=1.0f; }
        gemm3<<<dim3(8, 64, 1), blk, 0, stream>>>(gc);

        attn<<<dim3(1024), blk, 0, stream>>>(Qp, Kp, Vp, ctx);

        GemmArgs go;
        for (int i = 0; i < 3; i++) { go.X[i]=ctx; go.W[i]=Wob; go.B[i]=wo_b; go.O[i]=out; go.mode[i]=2; go.scale[i]=1.0f; }
        gemm3<<<dim3(8, 64, 1), blk, 0, stream>>>(go);
    }
}

// Round 3
// 338.372 us; speedup vs baseline: 1.2345x; 1.0369x over previous
//
#include <hip/hip_runtime.h>
#include <hip/hip_bf16.h>

typedef __attribute__((ext_vector_type(8))) short bf16x8;
typedef __attribute__((ext_vector_type(4))) short bf16x4;
typedef __attribute__((ext_vector_type(4))) float f32x4;
typedef __attribute__((address_space(3))) ushort lds_ushort;

#define MFMA32(a, b, c) __builtin_amdgcn_mfma_f32_16x16x32_bf16(a, b, c, 0, 0, 0)
#if __has_builtin(__builtin_amdgcn_mfma_f32_16x16x16bf16_1k)
#define HAVE_MFMA16K 1
#define MFMA16K(a, b, c) __builtin_amdgcn_mfma_f32_16x16x16bf16_1k(a, b, c, 0, 0, 0)
#else
#define HAVE_MFMA16K 0
#endif

// async global->LDS, 16B/lane; LDS dest = wave-uniform base + lane*16.
#define ASYNC16(g, l)                                                          \
    __builtin_amdgcn_global_load_lds(                                          \
        (const __attribute__((address_space(1))) unsigned int*)(g),            \
        (__attribute__((address_space(3))) unsigned int*)(l), 16, 0, 0)

// hw transpose read: per 16-lane group reads 128B window as 4x16 bf16
// row-major, lane l gets column (l&15). addr = window_base + (l&15)*8 bytes.
#define TR16(dst, addr, OFF)                                                   \
    asm volatile("ds_read_b64_tr_b16 %0, %1 offset:%2"                         \
                 : "=v"(dst) : "v"(addr), "i"(OFF))

__device__ __forceinline__ ushort f2bf(float f) {
    __hip_bfloat16 h = __float2bfloat16(f);  // RNE
    return *reinterpret_cast<ushort*>(&h);
}
// pack two f32 to bf16 pair in one instruction (T12; no builtin on gfx950).
__device__ __forceinline__ uint cvtpk(float a, float b) {
    uint r;
    asm("v_cvt_pk_bf16_f32 %0, %1, %2" : "=v"(r) : "v"(a), "v"(b));
    return r;
}

// log2(e)/sqrt(64), folded into Q projection -> attn does exp2(score) raw.
#define QSCALE 0.18033688011112042f

// ---------------------------------------------------------------------------
// fp32 -> bf16 convert, multi-range.
// ---------------------------------------------------------------------------
struct CvtArgs { const float* s[7]; ushort* d[7]; int nb[7]; };

__global__ __launch_bounds__(256) void cvtk(CvtArgs a) {
    const int z = blockIdx.y;
    if ((int)blockIdx.x >= a.nb[z]) return;
    const float* s = a.s[z];
    ushort* d = a.d[z];
    const size_t i = (size_t)blockIdx.x * 2048 + threadIdx.x * 8;
    float4 f0 = *(const float4*)&s[i];
    float4 f1 = *(const float4*)&s[i + 4];
    *(ushort4*)&d[i]     = make_ushort4(f2bf(f0.x), f2bf(f0.y), f2bf(f0.z), f2bf(f0.w));
    *(ushort4*)&d[i + 4] = make_ushort4(f2bf(f1.x), f2bf(f1.y), f2bf(f1.z), f2bf(f1.w));
}

// ---------------------------------------------------------------------------
// bf16 NT GEMM: out = (X@W^T + bias) * scale
//   mode 0: bf16 out [B=4,H=16,S=2048,64]  (Q scaled, K, V)
//   mode 2: fp32 out [8192,1024]           (final projection)
// R2: counted-vmcnt pipeline (T4): 2 K-tiles in flight, vmcnt(4) at step top
// (never 0 in steady state), raw barriers (no compiler vmcnt(0) drain).
// Step: wait own oldest tile -> B1 -> ds_read frags -> lgkmcnt(0)+B2 ->
// re-stage this buf for k+2 -> MFMA. Loads get ~2 K-steps of latency cover.
// XCD swizzle kept from R1 (neutral-to-positive).
// ---------------------------------------------------------------------------
struct GemmArgs {
    const ushort* X[3]; const ushort* W[3]; const float* B[3];
    void* O[3]; int mode[3]; float scale[3];
};

__global__ __launch_bounds__(256) void gemm3(GemmArgs g) {
    __shared__ __attribute__((aligned(16))) ushort As[2][128][32];
    __shared__ __attribute__((aligned(16))) ushort Bs[2][128][32];

    const int z = blockIdx.z;
    const ushort* __restrict__ X = g.X[z];
    const ushort* __restrict__ W = g.W[z];
    const float*  __restrict__ bias = g.B[z];
    const int mode = g.mode[z];
    const float scale = g.scale[z];

    const int tid  = threadIdx.x;
    const int lane = tid & 63;
    const int wave = tid >> 6;
    const int quad = lane >> 4;
    const int l16  = lane & 15;
    const int wm   = (wave >> 1) * 64;
    const int wn   = (wave & 1) * 64;

    const int flat = blockIdx.x + 8 * blockIdx.y;
    const int t    = (flat & 7) * 64 + (flat >> 3);
    const int m0   = (t >> 3) * 128;
    const int n0   = (t & 7) * 128;

    f32x4 acc[4][4];
#pragma unroll
    for (int i = 0; i < 4; i++)
#pragma unroll
        for (int j = 0; j < 4; j++) acc[i][j] = (f32x4)0.0f;

    // 4 ASYNC16 per thread per stage (2 per matrix); chunk c: row c>>2, colq c&3.
    auto stage = [&](int buf, int k0) {
#pragma unroll
        for (int j = 0; j < 2; j++) {
            const int c   = j * 256 + tid;
            const int r   = c >> 2;
            const int col = (c & 3) * 8;
            ASYNC16(&X[(size_t)(m0 + r) * 1024 + k0 + col],
                    &As[buf][0][0] + (size_t)(j * 256 + wave * 64) * 8);
            ASYNC16(&W[(size_t)(n0 + r) * 1024 + k0 + col],
                    &Bs[buf][0][0] + (size_t)(j * 256 + wave * 64) * 8);
        }
    };

    stage(0, 0);
    stage(1, 32);
    int cur = 0;

    for (int k0 = 0; k0 < 1024; k0 += 32) {
        // Own oldest tile (cur) has landed; tile k0+32 may still fly.
        if (k0 < 1024 - 32) {
            asm volatile("s_waitcnt vmcnt(4)" ::: "memory");
        } else {
            asm volatile("s_waitcnt vmcnt(0)" ::: "memory");
        }
        __builtin_amdgcn_s_barrier();        // B1: all waves' cur-tile landed
        __builtin_amdgcn_sched_barrier(0);

        bf16x8 af[4], bfr[4];
#pragma unroll
        for (int i = 0; i < 4; i++)
            af[i] = *(const bf16x8*)&As[cur][wm + i * 16 + l16][quad * 8];
#pragma unroll
        for (int j = 0; j < 4; j++)
            bfr[j] = *(const bf16x8*)&Bs[cur][wn + j * 16 + l16][quad * 8];
        asm volatile("s_waitcnt lgkmcnt(0)" ::: "memory");
        __builtin_amdgcn_sched_barrier(0);
        __builtin_amdgcn_s_barrier();        // B2: all waves done reading cur
        __builtin_amdgcn_sched_barrier(0);
        if (k0 + 64 < 1024) stage(cur, k0 + 64);  // reuse cur for tile k+2

#pragma unroll
        for (int i = 0; i < 4; i++)
#pragma unroll
            for (int j = 0; j < 4; j++)
                acc[i][j] = MFMA32(af[i], bfr[j], acc[i][j]);
        cur ^= 1;
    }

    // C/D: col = lane&15 (n), row = quad*4 + reg (m).
#pragma unroll
    for (int i = 0; i < 4; i++) {
#pragma unroll
        for (int j = 0; j < 4; j++) {
            const int n  = n0 + wn + j * 16 + l16;
            const float bb = bias[n];
#pragma unroll
            for (int r = 0; r < 4; r++) {
                const int m = m0 + wm + i * 16 + quad * 4 + r;
                const float val = (acc[i][j][r] + bb) * scale;
                if (mode == 2) {
                    ((float*)g.O[z])[(size_t)m * 1024 + n] = val;
                } else {
                    const int bat = m >> 11, s = m & 2047, h = n >> 6, d = n & 63;
                    ((ushort*)g.O[z])[((size_t)((bat * 16 + h) * 2048 + s)) * 64 + d]
                        = f2bf(val);
                }
            }
        }
    }
}

// ---------------------------------------------------------------------------
// Attention, P-in-registers. Block = (b,h) x 128 Q-rows; wave owns 32 rows.
// S^T = MFMA32(A=K, B=Q): lane holds (key=quad*4+r, query=l16) -> exp2 ->
// cvt_pk-packed bf16 regs ARE the A-frag of a K=16 MFMA. V staged via
// global_load_lds into 4x16-subtiled V' (source swizzle), PV B-frags via
// ds_read_b64_tr_b16. R2: row-sums via ones-B MFMA16K (C-layout = o's layout,
// so the epilogue shuffle reduction disappears); packs via v_cvt_pk_bf16_f32.
// K,V double-buffered, one barrier per tile. XCD swizzle on bh.
// ---------------------------------------------------------------------------
__global__ __launch_bounds__(256, 4) void attn(
    const ushort* __restrict__ Qp, const ushort* __restrict__ Kp,
    const ushort* __restrict__ Vp, ushort* __restrict__ ctx)
{
    __shared__ __attribute__((aligned(16))) ushort Ks[2][2 * 64 * 32];  // 2x8KB
    __shared__ __attribute__((aligned(16))) ushort Vs[2][64 * 64];      // 2x8KB

    const int tid  = threadIdx.x;
    const int lane = tid & 63;
    const int wave = tid >> 6;
    const int quad = lane >> 4;
    const int l16  = lane & 15;

    const int id = blockIdx.x;
    const int bh = (id & 7) * 8 + ((id >> 3) & 7);  // XCD-contiguous bh
    const int q0 = (id >> 6) * 128;
    const int b  = bh >> 4, h = bh & 15;

    const ushort* Qg = Qp + ((size_t)bh * 2048 + q0) * 64;
    const ushort* Kg = Kp + (size_t)bh * 2048 * 64;
    const ushort* Vg = Vp + (size_t)bh * 2048 * 64;

    // Loop-invariant Q fragments (B-operand: n=l16=query, k=quad*8+e).
    bf16x8 aq[2][2];
#pragma unroll
    for (int st = 0; st < 2; st++)
#pragma unroll
        for (int kk = 0; kk < 2; kk++)
            aq[st][kk] = *(const bf16x8*)&Qg[(size_t)(wave * 32 + st * 16 + l16) * 64
                                            + kk * 32 + quad * 8];

    f32x4 o[2][4];
#pragma unroll
    for (int st = 0; st < 2; st++)
#pragma unroll
        for (int jd = 0; jd < 4; jd++) o[st][jd] = (f32x4)0.0f;
#if HAVE_MFMA16K
    f32x4 ls[2] = {(f32x4)0.0f, (f32x4)0.0f};  // row sums, o-compatible layout
    union { uint u[2]; bf16x4 v; } ones;
    ones.u[0] = 0x3F803F80u; ones.u[1] = 0x3F803F80u;  // bf16 1.0 x4
#else
    float lsum[2] = {0.f, 0.f};
#endif

    // K tile: natural [half][row][32] layout. V tile: 4x16-subtiled V' via
    // source-swizzled async chunks; global src stays 128B-coalesced per 8 lanes.
    auto stage = [&](int buf, int n0) {
#pragma unroll
        for (int j = 0; j < 2; j++) {
            const int c    = j * 256 + tid;
            const int colq = c & 3;
            const int row  = (c >> 2) & 63;
            const int half = c >> 8;
            ASYNC16(&Kg[(size_t)(n0 + row) * 64 + half * 32 + colq * 8],
                    &Ks[buf][0] + (size_t)(j * 256 + wave * 64) * 8);
        }
#pragma unroll
        for (int j = 0; j < 2; j++) {
            const int c   = j * 256 + tid;
            const int key = ((c >> 5) << 2) | ((c >> 1) & 3);
            const int d   = (((c >> 3) & 3) << 4) | ((c & 1) << 3);
            ASYNC16(&Vg[(size_t)(n0 + key) * 64 + d],
                    &Vs[buf][0] + (size_t)(j * 256 + wave * 64) * 8);
        }
    };

    stage(0, 0);
    int cur = 0;

    for (int n0 = 0; n0 < 2048; n0 += 64) {
        __syncthreads();  // drains vmcnt: buf 'cur' is ready; prev reads done
        if (n0 + 64 < 2048) stage(cur ^ 1, n0 + 64);  // flies under compute

        // ---- S^T: 8 tiles (kb keys x st strips), exp2 + pack in-register ----
        uint pk[4][2][2];
#pragma unroll
        for (int kb = 0; kb < 4; kb++) {
            bf16x8 kf0 = *(const bf16x8*)&Ks[cur][(size_t)(kb * 16 + l16) * 32 + quad * 8];
            bf16x8 kf1 = *(const bf16x8*)&Ks[cur][(size_t)(64 + kb * 16 + l16) * 32 + quad * 8];
#pragma unroll
            for (int st = 0; st < 2; st++) {
                f32x4 s = (f32x4)0.0f;
                s = MFMA32(kf0, aq[st][0], s);
                s = MFMA32(kf1, aq[st][1], s);
                float e0 = __builtin_amdgcn_exp2f(s[0]);
                float e1 = __builtin_amdgcn_exp2f(s[1]);
                float e2 = __builtin_amdgcn_exp2f(s[2]);
                float e3 = __builtin_amdgcn_exp2f(s[3]);
                pk[kb][st][0] = cvtpk(e0, e1);
                pk[kb][st][1] = cvtpk(e2, e3);
#if !HAVE_MFMA16K
                lsum[st] += (e0 + e1) + (e2 + e3);
#endif
            }
        }

#if HAVE_MFMA16K
        // ---- PV: B-frags via hw transpose reads from subtiled V' ----
        const lds_ushort* vp = (const lds_ushort*)&Vs[cur][0] + quad * 256 + l16 * 4;
        bf16x4 vf[4][4];  // [jd][kb]
#define TRISSUE(JD)                                                            \
        TR16(vf[JD][0], vp, (JD) * 128 + 0);                                   \
        TR16(vf[JD][1], vp, (JD) * 128 + 2048);                                \
        TR16(vf[JD][2], vp, (JD) * 128 + 4096);                                \
        TR16(vf[JD][3], vp, (JD) * 128 + 6144);
        TRISSUE(0) TRISSUE(1) TRISSUE(2) TRISSUE(3)

        // Row-sum MFMAs (register-only) fill the tr-read latency window:
        // C[q][*] += sum_k P[q][k]; reg r holds query quad*4+r = o's layout.
#pragma unroll
        for (int kb = 0; kb < 4; kb++) {
#pragma unroll
            for (int st = 0; st < 2; st++) {
                union { uint u[2]; bf16x4 v; } pf;
                pf.u[0] = pk[kb][st][0];
                pf.u[1] = pk[kb][st][1];
                ls[st] = MFMA16K(pf.v, ones.v, ls[st]);
            }
        }

        // counted lgkmcnt: jd group ready when <=12-4*jd outstanding (FIFO,
        // trs are oldest). sched_barrier(0) after each wait (rule #18).
#define PVWAIT(N)                                                              \
        asm volatile("s_waitcnt lgkmcnt(" #N ")" ::: "memory");                \
        __builtin_amdgcn_sched_barrier(0);
#define PVJD(JD)                                                               \
        _Pragma("unroll")                                                      \
        for (int kb = 0; kb < 4; kb++) {                                       \
            _Pragma("unroll")                                                  \
            for (int st = 0; st < 2; st++) {                                   \
                union { uint u[2]; bf16x4 v; } pf;                             \
                pf.u[0] = pk[kb][st][0];                                       \
                pf.u[1] = pk[kb][st][1];                                       \
                o[st][JD] = MFMA16K(pf.v, vf[JD][kb], o[st][JD]);              \
            }                                                                  \
        }
        __builtin_amdgcn_s_setprio(1);
        PVWAIT(12) PVJD(0)
        PVWAIT(8)  PVJD(1)
        PVWAIT(4)  PVJD(2)
        PVWAIT(0)  PVJD(3)
        __builtin_amdgcn_s_setprio(0);
#else
        // Fallback: assemble K=32 A-frags via ds_bpermute, gather V from the
        // subtiled V' with scalar reads, PV with MFMA32. (Correctness path.)
        const int addr0 = 4 * ((2 * (quad & 1)) * 16 + l16);
        const int addr1 = addr0 + 64;
#pragma unroll
        for (int kt = 0; kt < 2; kt++) {
            bf16x8 apf[2];
#pragma unroll
            for (int st = 0; st < 2; st++) {
                union { uint u[4]; bf16x8 v; } t;
#pragma unroll
                for (int j = 0; j < 4; j++) {
                    uint src = (quad & 2) ? pk[kt * 2 + 1][st][j & 1]
                                          : pk[kt * 2][st][j & 1];
                    t.u[j] = (uint)__builtin_amdgcn_ds_bpermute(
                        (j >> 1) ? addr1 : addr0, (int)src);
                }
                apf[st] = t.v;
            }
#pragma unroll
            for (int jd = 0; jd < 4; jd++) {
                union { ushort s[8]; bf16x8 v; } vv;
#pragma unroll
                for (int e = 0; e < 8; e++) {
                    const int key = kt * 32 + quad * 8 + e;
                    const int d   = jd * 16 + l16;
                    vv.s[e] = Vs[cur][(key >> 2) * 256 + (d >> 4) * 64
                                      + (key & 3) * 16 + (d & 15)];
                }
#pragma unroll
                for (int st = 0; st < 2; st++)
                    o[st][jd] = MFMA32(apf[st], vv.v, o[st][jd]);
            }
        }
#endif
        cur ^= 1;
    }

#if HAVE_MFMA16K
    // ls[st][r] is already the row sum for query quad*4+r — no shuffles.
#pragma unroll
    for (int st = 0; st < 2; st++) {
        float inv[4];
#pragma unroll
        for (int r = 0; r < 4; r++) inv[r] = 1.0f / ls[st][r];
#pragma unroll
        for (int jd = 0; jd < 4; jd++) {
#pragma unroll
            for (int r = 0; r < 4; r++) {
                const int s = q0 + wave * 32 + st * 16 + quad * 4 + r;
                ctx[((size_t)(b * 2048 + s)) * 1024 + h * 64 + jd * 16 + l16] =
                    f2bf(o[st][jd][r] * inv[r]);
            }
        }
    }
#else
    // lsum holds per-(l16,quad) partials for query=l16: reduce over quads.
#pragma unroll
    for (int st = 0; st < 2; st++) {
        float lsv = lsum[st];
        lsv += __shfl_xor(lsv, 16, 64);
        lsv += __shfl_xor(lsv, 32, 64);
        float inv[4];
#pragma unroll
        for (int r = 0; r < 4; r++)
            inv[r] = 1.0f / __shfl(lsv, quad * 4 + r, 64);
#pragma unroll
        for (int jd = 0; jd < 4; jd++) {
#pragma unroll
            for (int r = 0; r < 4; r++) {
                const int s = q0 + wave * 32 + st * 16 + quad * 4 + r;
                ctx[((size_t)(b * 2048 + s)) * 1024 + h * 64 + jd * 16 + l16] =
                    f2bf(o[st][jd][r] * inv[r]);
            }
        }
    }
#endif
}

extern "C" void kernel_launch(void* const* d_in, const int* in_sizes, int n_in,
                              void* d_out, int out_size, void* d_ws, size_t ws_size,
                              hipStream_t stream) {
    const float* q    = (const float*)d_in[0];
    const float* k    = (const float*)d_in[1];
    const float* v    = (const float*)d_in[2];
    const float* wq_w = (const float*)d_in[3];
    const float* wq_b = (const float*)d_in[4];
    const float* wk_w = (const float*)d_in[5];
    const float* wk_b = (const float*)d_in[6];
    const float* wv_w = (const float*)d_in[7];
    const float* wv_b = (const float*)d_in[8];
    const float* wo_w = (const float*)d_in[9];
    const float* wo_b = (const float*)d_in[10];
    float* out = (float*)d_out;

    const size_t NE = (size_t)4 * 2048 * 1024;
    const size_t NW = (size_t)1024 * 1024;
    const size_t need_fused = (6 * NE + 4 * NW) * 2;

    dim3 blk(256);

    if (ws_size >= need_fused) {
        ushort* Xq = (ushort*)d_ws;
        ushort* Xk = Xq + NE;
        ushort* Xv = Xk + NE;
        ushort* Wq = Xv + NE;
        ushort* Wk = Wq + NW;
        ushort* Wv = Wk + NW;
        ushort* Wo = Wv + NW;
        ushort* Qp = Wo + NW;
        ushort* Kp = Qp + NE;
        ushort* Vp = Kp + NE;
        ushort* ctx = Xq;

        CvtArgs ca;
        ca.s[0]=q;    ca.d[0]=Xq; ca.nb[0]=4096;
        ca.s[1]=k;    ca.d[1]=Xk; ca.nb[1]=4096;
        ca.s[2]=v;    ca.d[2]=Xv; ca.nb[2]=4096;
        ca.s[3]=wq_w; ca.d[3]=Wq; ca.nb[3]=512;
        ca.s[4]=wk_w; ca.d[4]=Wk; ca.nb[4]=512;
        ca.s[5]=wv_w; ca.d[5]=Wv; ca.nb[5]=512;
        ca.s[6]=wo_w; ca.d[6]=Wo; ca.nb[6]=512;
        cvtk<<<dim3(4096, 7), blk, 0, stream>>>(ca);

        GemmArgs ga;
        ga.X[0]=Xq; ga.W[0]=Wq; ga.B[0]=wq_b; ga.O[0]=Qp; ga.mode[0]=0; ga.scale[0]=QSCALE;
        ga.X[1]=Xk; ga.W[1]=Wk; ga.B[1]=wk_b; ga.O[1]=Kp; ga.mode[1]=0; ga.scale[1]=1.0f;
        ga.X[2]=Xv; ga.W[2]=Wv; ga.B[2]=wv_b; ga.O[2]=Vp; ga.mode[2]=0; ga.scale[2]=1.0f;
        gemm3<<<dim3(8, 64, 3), blk, 0, stream>>>(ga);

        attn<<<dim3(1024), blk, 0, stream>>>(Qp, Kp, Vp, ctx);

        GemmArgs go;
        go.X[0]=ctx; go.W[0]=Wo; go.B[0]=wo_b; go.O[0]=out; go.mode[0]=2; go.scale[0]=1.0f;
        go.X[1]=go.X[0]; go.W[1]=go.W[0]; go.B[1]=go.B[0]; go.O[1]=go.O[0]; go.mode[1]=2; go.scale[1]=1.0f;
        go.X[2]=go.X[0]; go.W[2]=go.W[0]; go.B[2]=go.B[0]; go.O[2]=go.O[0]; go.mode[2]=2; go.scale[2]=1.0f;
        gemm3<<<dim3(8, 64, 1), blk, 0, stream>>>(go);
    } else {
        // Serial fallback (68 MB): Xb reused per projection, then as ctx.
        ushort* Xb  = (ushort*)d_ws;
        ushort* Wb  = Xb + NE;
        ushort* Wob = Wb + NW;
        ushort* Qp  = Wob + NW;
        ushort* Kp  = Qp + NE;
        ushort* Vp  = Kp + NE;
        ushort* ctx = Xb;

        CvtArgs c0;
        c0.s[0]=q;    c0.d[0]=Xb;  c0.nb[0]=4096;
        c0.s[1]=wq_w; c0.d[1]=Wb;  c0.nb[1]=512;
        c0.s[2]=wo_w; c0.d[2]=Wob; c0.nb[2]=512;
        for (int i = 3; i < 7; i++) { c0.s[i]=q; c0.d[i]=Xb; c0.nb[i]=0; }
        cvtk<<<dim3(4096, 3), blk, 0, stream>>>(c0);
        GemmArgs ga;
        for (int i = 0; i < 3; i++) { ga.X[i]=Xb; ga.W[i]=Wb; ga.B[i]=wq_b; ga.O[i]=Qp; ga.mode[i]=0; ga.scale[i]=QSCALE; }
        gemm3<<<dim3(8, 64, 1), blk, 0, stream>>>(ga);

        CvtArgs c1;
        c1.s[0]=k;    c1.d[0]=Xb; c1.nb[0]=4096;
        c1.s[1]=wk_w; c1.d[1]=Wb; c1.nb[1]=512;
        for (int i = 2; i < 7; i++) { c1.s[i]=k; c1.d[i]=Xb; c1.nb[i]=0; }
        cvtk<<<dim3(4096, 2), blk, 0, stream>>>(c1);
        GemmArgs gb;
        for (int i = 0; i < 3; i++) { gb.X[i]=Xb; gb.W[i]=Wb; gb.B[i]=wk_b; gb.O[i]=Kp; gb.mode[i]=0; gb.scale[i]=1.0f; }
        gemm3<<<dim3(8, 64, 1), blk, 0, stream>>>(gb);

        CvtArgs c2;
        c2.s[0]=v;    c2.d[0]=Xb; c2.nb[0]=4096;
        c2.s[1]=wv_w; c2.d[1]=Wb; c2.nb[1]=512;
        for (int i = 2; i < 7; i++) { c2.s[i]=v; c2.d[i]=Xb; c2.nb[i]=0; }
        cvtk<<<dim3(4096, 2), blk, 0, stream>>>(c2);
        GemmArgs gc;
        for (int i = 0; i < 3; i++) { gc.X[i]=Xb; gc.W[i]=Wb; gc.B[i]=wv_b; gc.O[i]=Vp; gc.mode[i]=0; gc.scale[i]=1.0f; }
        gemm3<<<dim3(8, 64, 1), blk, 0, stream>>>(gc);

        attn<<<dim3(1024), blk, 0, stream>>>(Qp, Kp, Vp, ctx);

        GemmArgs go;
        for (int i = 0; i < 3; i++) { go.X[i]=ctx; go.W[i]=Wob; go.B[i]=wo_b; go.O[i]=out; go.mode[i]=2; go.scale[i]=1.0f; }
        gemm3<<<dim3(8, 64, 1), blk, 0, stream>>>(go);
    }
}